// Round 4
// baseline (892.716 us; speedup 1.0000x reference)
//
#include <hip/hip_runtime.h>

typedef unsigned short u16;
typedef unsigned int u32;

typedef __bf16 bf16x8 __attribute__((ext_vector_type(8)));
typedef float f32x4 __attribute__((ext_vector_type(4)));

#define SEQ 2048
#define NH 32
#define NKV 8
#define HDIM 128
#define QKVW 6144   // fused QKV row width: 4096 Q + 1024 K + 1024 V
#define KCOL 4096
#define VCOL 5120

__device__ __forceinline__ float b2f(u16 u) {
    return __uint_as_float(((u32)u) << 16);
}
__device__ __forceinline__ u16 f2bf(float f) {
    u32 u = __float_as_uint(f);
    u += 0x7fff + ((u >> 16) & 1);   // RNE
    return (u16)(u >> 16);
}

#define GLDS16(g, l)                                                            \
    __builtin_amdgcn_global_load_lds(                                           \
        (const __attribute__((address_space(1))) void*)(g),                     \
        (__attribute__((address_space(3))) void*)(l), 16, 0, 0)

// ------- transpose + fp32->bf16 convert: in (K,N) f32 -> out (N,K) bf16 -----
__global__ __launch_bounds__(1024) void transcvt_k(const float* __restrict__ in,
                                                   u16* __restrict__ out,
                                                   int K, int N) {
    __shared__ float tile[32][33];
    int n0 = blockIdx.x * 32, k0 = blockIdx.y * 32;
    tile[threadIdx.y][threadIdx.x] = in[(size_t)(k0 + threadIdx.y) * N + n0 + threadIdx.x];
    __syncthreads();
    out[(size_t)(n0 + threadIdx.y) * K + k0 + threadIdx.x] = f2bf(tile[threadIdx.x][threadIdx.y]);
}

// ---------------- fp32 -> bf16 convert, 8 elems/thread ----------------------
__global__ __launch_bounds__(256) void cvt_k(const float* __restrict__ in,
                                             u16* __restrict__ out) {
    size_t i = ((size_t)blockIdx.x * 256 + threadIdx.x) * 8;
    float4 f0 = *(const float4*)(in + i);
    float4 f1 = *(const float4*)(in + i + 4);
    union { uint4 u4; u16 h[8]; } pk;
    pk.h[0] = f2bf(f0.x); pk.h[1] = f2bf(f0.y);
    pk.h[2] = f2bf(f0.z); pk.h[3] = f2bf(f0.w);
    pk.h[4] = f2bf(f1.x); pk.h[5] = f2bf(f1.y);
    pk.h[6] = f2bf(f1.z); pk.h[7] = f2bf(f1.w);
    *(uint4*)(out + i) = pk.u4;
}

// ---- 256x256-tile 8-phase GEMM: C(M,N) = A(M,K) @ BT(N,K)^T, bf16 in ------
// m201 template: 512 thr / 8 waves (2Mx4N), BK=64, 128 KiB double-buffered
// LDS, XOR-swizzled rows (T2), counted vmcnt (T3+T4), setprio (T5).
// Requires M%256==0, N%256==0, K%128==0.
template <bool OUT_F32>
__global__ __launch_bounds__(512, 2) void gemm256(const u16* __restrict__ A,
                                                  const u16* __restrict__ BT,
                                                  void* __restrict__ Cv,
                                                  int M, int N, int K) {
    // [buf][ A 32KB | B 32KB ] x2 = 128 KiB. Row-major [256][64] bf16,
    // 128-B rows, read-side swizzle byte ^= ((row&7)<<4) (staged via
    // pre-swizzled global source: rule #21 both-sides-or-neither).
    __shared__ __align__(16) char L[131072];
    const int t = threadIdx.x, lane = t & 63, w = t >> 6;
    const int wr = w >> 2, wc = w & 3;          // wave grid 2(M) x 4(N)
    const int m0 = blockIdx.y * 256, n0 = blockIdx.x * 256;
    const int r16 = lane & 15;
    const int woff = w * 1024;                  // per-wave slot in each 8KB issue
    const int w8l = w * 8 + (lane >> 3);        // row within a 64-row issue block
    const int cswz = ((lane & 7) ^ (lane >> 3)) * 8;  // pre-swizzled src col (elems)
    const u16* sA = A + (size_t)(m0 + w8l) * K + cswz;
    const u16* sB = BT + (size_t)(n0 + w8l) * K + cswz;

    // read-side swizzled in-row byte offsets for kk=0 / kk=1 (32-col k slices)
    const int acol0 = ((lane >> 4) * 16) ^ ((lane & 7) << 4);
    const int acol1 = (((lane >> 4) * 16) + 64) ^ ((lane & 7) << 4);
    const char* arowp = L + (wr * 128 + r16) * 128;          // A frag row base
    const char* browp = L + 32768 + (wc * 64 + r16) * 128;   // B frag row base

    f32x4 acc[8][4] = {};
    bf16x8 a[4][2], b0[2][2], b1[2][2];

    // stage one half-tile (128 rows = 2 x 8KB issues) of A (isB=0) or B (isB=1)
    auto stage = [&](int bufi, int isB, int h, int kt) {
        const u16* s = isB ? sB : sA;
        char* d = (char*)L + bufi * 65536 + isB * 32768 + h * 16384 + woff;
        GLDS16(s + (size_t)(h * 128) * K + kt, d);
        GLDS16(s + (size_t)(h * 128 + 64) * K + kt, d + 8192);
    };

    const int NT = K >> 6;
    // prologue: tile0 fully + tile1.A0; drain tile0 (leave tile1.A0 in flight)
    stage(0, 0, 0, 0); stage(0, 0, 1, 0); stage(0, 1, 0, 0); stage(0, 1, 1, 0);
    if (NT > 1) {
        stage(1, 0, 0, 64);
        asm volatile("s_waitcnt vmcnt(2)" ::: "memory");
    } else {
        asm volatile("s_waitcnt vmcnt(0)" ::: "memory");
    }
    __builtin_amdgcn_s_barrier();
    __builtin_amdgcn_sched_barrier(0);

    for (int T = 0; T < NT; ++T) {
        const int buf = T & 1;
        const char* Ab = arowp + buf * 65536;
        const char* Bb = browp + buf * 65536;
        const int ktn = (T + 1) << 6, ktn2 = (T + 2) << 6;

        // ---------------- P1: a[0-3], b[0-1]  |  stage (T+1).A1 ----------------
#pragma unroll
        for (int mi = 0; mi < 4; ++mi) {
            a[mi][0] = *(const bf16x8*)(Ab + mi * 2048 + acol0);
            a[mi][1] = *(const bf16x8*)(Ab + mi * 2048 + acol1);
        }
#pragma unroll
        for (int ni = 0; ni < 2; ++ni) {
            b0[ni][0] = *(const bf16x8*)(Bb + ni * 2048 + acol0);
            b0[ni][1] = *(const bf16x8*)(Bb + ni * 2048 + acol1);
        }
        if (T + 1 < NT) stage(buf ^ 1, 0, 1, ktn);
        __builtin_amdgcn_s_barrier();
        __builtin_amdgcn_sched_barrier(0);
        asm volatile("s_waitcnt lgkmcnt(0)" ::: "memory");
        __builtin_amdgcn_s_setprio(1);
#pragma unroll
        for (int mi = 0; mi < 4; ++mi)
#pragma unroll
            for (int ni = 0; ni < 2; ++ni) {
                acc[mi][ni] = __builtin_amdgcn_mfma_f32_16x16x32_bf16(a[mi][0], b0[ni][0], acc[mi][ni], 0, 0, 0);
                acc[mi][ni] = __builtin_amdgcn_mfma_f32_16x16x32_bf16(a[mi][1], b0[ni][1], acc[mi][ni], 0, 0, 0);
            }
        __builtin_amdgcn_s_setprio(0);
        __builtin_amdgcn_s_barrier();
        __builtin_amdgcn_sched_barrier(0);

        // ---------------- P2: b[2-3]          |  stage (T+1).B0 ----------------
#pragma unroll
        for (int ni = 0; ni < 2; ++ni) {
            b1[ni][0] = *(const bf16x8*)(Bb + (ni + 2) * 2048 + acol0);
            b1[ni][1] = *(const bf16x8*)(Bb + (ni + 2) * 2048 + acol1);
        }
        if (T + 1 < NT) stage(buf ^ 1, 1, 0, ktn);
        __builtin_amdgcn_s_barrier();
        __builtin_amdgcn_sched_barrier(0);
        asm volatile("s_waitcnt lgkmcnt(0)" ::: "memory");
        __builtin_amdgcn_s_setprio(1);
#pragma unroll
        for (int mi = 0; mi < 4; ++mi)
#pragma unroll
            for (int ni = 0; ni < 2; ++ni) {
                acc[mi][ni + 2] = __builtin_amdgcn_mfma_f32_16x16x32_bf16(a[mi][0], b1[ni][0], acc[mi][ni + 2], 0, 0, 0);
                acc[mi][ni + 2] = __builtin_amdgcn_mfma_f32_16x16x32_bf16(a[mi][1], b1[ni][1], acc[mi][ni + 2], 0, 0, 0);
            }
        __builtin_amdgcn_s_setprio(0);
        __builtin_amdgcn_s_barrier();
        __builtin_amdgcn_sched_barrier(0);

        // ---------------- P3: a[4-7]          |  stage (T+1).B1 ----------------
        // (last ds_reads of buf this tile)
#pragma unroll
        for (int mi = 0; mi < 4; ++mi) {
            a[mi][0] = *(const bf16x8*)(Ab + (mi + 4) * 2048 + acol0);
            a[mi][1] = *(const bf16x8*)(Ab + (mi + 4) * 2048 + acol1);
        }
        if (T + 1 < NT) stage(buf ^ 1, 1, 1, ktn);
        __builtin_amdgcn_s_barrier();
        __builtin_amdgcn_sched_barrier(0);
        asm volatile("s_waitcnt lgkmcnt(0)" ::: "memory");
        __builtin_amdgcn_s_setprio(1);
#pragma unroll
        for (int mi = 0; mi < 4; ++mi)
#pragma unroll
            for (int ni = 0; ni < 2; ++ni) {
                acc[mi + 4][ni] = __builtin_amdgcn_mfma_f32_16x16x32_bf16(a[mi][0], b0[ni][0], acc[mi + 4][ni], 0, 0, 0);
                acc[mi + 4][ni] = __builtin_amdgcn_mfma_f32_16x16x32_bf16(a[mi][1], b0[ni][1], acc[mi + 4][ni], 0, 0, 0);
            }
        __builtin_amdgcn_s_setprio(0);
        __builtin_amdgcn_s_barrier();
        __builtin_amdgcn_sched_barrier(0);

        // ---------------- P4: (no reads)      |  stage (T+2).A0 into buf -------
        // safe: all waves' reads of buf completed before P3's closing barrier.
        if (T + 2 < NT) stage(buf, 0, 0, ktn2);
        __builtin_amdgcn_s_setprio(1);
#pragma unroll
        for (int mi = 0; mi < 4; ++mi)
#pragma unroll
            for (int ni = 0; ni < 2; ++ni) {
                acc[mi + 4][ni + 2] = __builtin_amdgcn_mfma_f32_16x16x32_bf16(a[mi][0], b1[ni][0], acc[mi + 4][ni + 2], 0, 0, 0);
                acc[mi + 4][ni + 2] = __builtin_amdgcn_mfma_f32_16x16x32_bf16(a[mi][1], b1[ni][1], acc[mi + 4][ni + 2], 0, 0, 0);
            }
        __builtin_amdgcn_s_setprio(0);
        // counted drain: tile T+1 fully landed; (T+2).A0 (2 loads) stays in flight
        if (T + 2 < NT) asm volatile("s_waitcnt vmcnt(2)" ::: "memory");
        else            asm volatile("s_waitcnt vmcnt(0)" ::: "memory");
        __builtin_amdgcn_s_barrier();
        __builtin_amdgcn_sched_barrier(0);
    }

    const int r0 = (lane >> 4) * 4;
#pragma unroll
    for (int mi = 0; mi < 8; ++mi) {
#pragma unroll
        for (int r = 0; r < 4; ++r) {
            size_t row = (size_t)(m0 + wr * 128 + mi * 16 + r0 + r) * N + n0 + wc * 64;
#pragma unroll
            for (int ni = 0; ni < 4; ++ni) {
                if constexpr (OUT_F32)
                    ((float*)Cv)[row + ni * 16 + r16] = acc[mi][ni][r];
                else
                    ((u16*)Cv)[row + ni * 16 + r16] = f2bf(acc[mi][ni][r]);
            }
        }
    }
}

// ------------- RoPE in-place on QKV buffer (row stride QKVW) ----------------
__global__ __launch_bounds__(256) void rope_k(u16* __restrict__ T, int col0,
                                              const float* __restrict__ cosb,
                                              const float* __restrict__ sinb,
                                              int nh) {
    int i = blockIdx.x * 256 + threadIdx.x;
    int p = i & 63;
    int h = (i >> 6) % nh;
    int bs = i / (64 * nh);
    int s = bs & (SEQ - 1);
    size_t base = (size_t)bs * QKVW + col0 + h * HDIM + 2 * p;
    ushort2 v = *(ushort2*)(T + base);
    float te = b2f(v.x), to = b2f(v.y);
    float c = cosb[s * 64 + p], sn = sinb[s * 64 + p];
    ushort2 o;
    o.x = f2bf(te * c - to * sn);
    o.y = f2bf(te * sn + to * c);
    *(ushort2*)(T + base) = o;
}

// ---- V transpose: QKV[token][VCOL + g*128 + d] -> VtG[(b*8+g)*128 + d][s] ---
__global__ __launch_bounds__(1024) void vtrans_k(const u16* __restrict__ QKV,
                                                 u16* __restrict__ VtG) {
    __shared__ u16 tile[32][33];
    int s0 = blockIdx.x * 32, d0 = blockIdx.y * 32, plane = blockIdx.z;
    int b = plane >> 3, g = plane & 7;
    tile[threadIdx.y][threadIdx.x] =
        QKV[(size_t)(b * SEQ + s0 + threadIdx.y) * QKVW + VCOL + g * HDIM + d0 + threadIdx.x];
    __syncthreads();
    VtG[((size_t)plane * HDIM + d0 + threadIdx.y) * SEQ + s0 + threadIdx.x] =
        tile[threadIdx.x][threadIdx.y];
}

// --------- MFMA flash attention: 4 waves, 64 Q-rows, KVBLK=64 ---------------
// Pipelined: dbuf K [64][128] + V^T [128][64] tiles staged via global_load_lds
// (pre-swizzled source, XOR-swizzled reads), depth-2 prefetch, counted
// vmcnt(8) (never 0 in-loop), setprio around MFMA chains.
__global__ __launch_bounds__(256) void fattn_k(const u16* __restrict__ QKV,
                                               const u16* __restrict__ VtG,
                                               u16* __restrict__ O) {
    // K: 2 x 16 KB @ 0 | V^T: 2 x 16 KB @ 32768 | Ps: 4 x [16][72] u16 @ 65536
    __shared__ __align__(16) char L[74752];

    const int q0 = (gridDim.x - 1 - blockIdx.x) * 64;  // big tiles first (LPT)
    const int h = blockIdx.y, b = blockIdx.z;
    const int g = h >> 2;  // N_REP = 4
    const int t = threadIdx.x, lane = t & 63, w = t >> 6;
    const int row16 = lane & 15, g16 = lane >> 4;
    const int q8 = g16 * 8, q84 = g16 * 4;
    const int swz = (row16 & 7) << 4;                 // read-side XOR (bytes)
    const float scale = 0.08838834764831845f;  // 1/sqrt(128)

    u16* Ps = (u16*)(L + 65536) + w * (16 * 72);      // 144-B rows (9x16B)

    const u16* kbase = QKV + (size_t)b * SEQ * QKVW + KCOL + g * HDIM;
    const u16* vtp = VtG + (size_t)(b * NKV + g) * HDIM * SEQ;

    // Q fragments (oldest VMEM ops; prologue vmcnt covers them too)
    bf16x8 qf[4];
    {
        const u16* qptr = QKV + (size_t)(b * SEQ + q0 + w * 16 + row16) * QKVW + h * HDIM;
#pragma unroll
        for (int c = 0; c < 4; ++c) qf[c] = *(const bf16x8*)(qptr + c * 32 + q8);
    }

    // staging: 16 x 1KB issues each for K and V^T; wave w does issues w*4..w*4+3.
    // LDS slot s of row r holds global 16B-chunk s ^ (r&7)  (T2 involution).
    const int krl = lane >> 4, kch = lane & 15;       // K: 4 rows/issue, 16 chunks
    const int vrl = lane >> 3, vch = lane & 7;        // V: 8 rows/issue,  8 chunks
    auto stage = [&](int bufi, int jb) {
#pragma unroll
        for (int jj = 0; jj < 4; ++jj) {
            int j = w * 4 + jj;
            int r = j * 4 + krl;
            int sc = kch ^ (r & 7);
            GLDS16(kbase + (size_t)(jb + r) * QKVW + sc * 8,
                   (char*)L + bufi * 16384 + j * 1024);
        }
#pragma unroll
        for (int jj = 0; jj < 4; ++jj) {
            int j = w * 4 + jj;
            int r = j * 8 + vrl;
            int sc = vch ^ (vrl & 7);
            GLDS16(vtp + (size_t)r * SEQ + jb + sc * 8,
                   (char*)L + 32768 + bufi * 16384 + j * 1024);
        }
    };

    f32x4 o[8];
#pragma unroll
    for (int c = 0; c < 8; ++c) o[c] = (f32x4){0.f, 0.f, 0.f, 0.f};
    float lsum[4] = {0.f, 0.f, 0.f, 0.f};

    const int NT = q0 / 64 + 1;
    // prologue: stage tile0 + tile1; wait Q + tile0 (leave tile1's 8 in flight)
    stage(0, 0);
    if (NT > 1) {
        stage(1, 64);
        asm volatile("s_waitcnt vmcnt(8)" ::: "memory");
    } else {
        asm volatile("s_waitcnt vmcnt(0)" ::: "memory");
    }
    __builtin_amdgcn_s_barrier();
    __builtin_amdgcn_sched_barrier(0);

    for (int T = 0; T < NT; ++T) {
        const int jb = T * 64;
        const char* Kb = (const char*)L + (T & 1) * 16384;
        const char* Vb = (const char*)L + 32768 + (T & 1) * 16384;

        // S = Q K^T (16x64), exp (no-max softmax), P -> per-wave LDS
#pragma unroll
        for (int sub = 0; sub < 4; ++sub) {
            f32x4 sa = {0.f, 0.f, 0.f, 0.f};
            const int srow = sub * 16 + row16;
            __builtin_amdgcn_s_setprio(1);
#pragma unroll
            for (int c = 0; c < 4; ++c) {
                bf16x8 kf = *(const bf16x8*)(Kb + srow * 256 + (((c * 4 + g16) << 4) ^ swz));
                sa = __builtin_amdgcn_mfma_f32_16x16x32_bf16(qf[c], kf, sa, 0, 0, 0);
            }
            __builtin_amdgcn_s_setprio(0);
            const int kcol = jb + sub * 16 + row16;
            const int qrow = q0 + w * 16 + q84;
#pragma unroll
            for (int r = 0; r < 4; ++r) {
                float p = (kcol <= qrow + r) ? __expf(fminf(sa[r] * scale, 80.f)) : 0.f;
                lsum[r] += p;
                Ps[(q84 + r) * 72 + sub * 16 + row16] = f2bf(p);
            }
        }
        // P·V (per-wave Ps: same-wave ordering, no barrier needed)
#pragma unroll
        for (int kk = 0; kk < 2; ++kk) {
            bf16x8 pf = *(const bf16x8*)(Ps + row16 * 72 + kk * 32 + q8);
            __builtin_amdgcn_s_setprio(1);
#pragma unroll
            for (int c = 0; c < 8; ++c) {
                bf16x8 vf = *(const bf16x8*)(Vb + (c * 16 + row16) * 128 + (((kk * 4 + g16) << 4) ^ swz));
                o[c] = __builtin_amdgcn_mfma_f32_16x16x32_bf16(pf, vf, o[c], 0, 0, 0);
            }
            __builtin_amdgcn_s_setprio(0);
        }

        if (T + 1 < NT) {
            __builtin_amdgcn_s_barrier();          // all waves done reading buf
            __builtin_amdgcn_sched_barrier(0);
            if (T + 2 < NT) {
                stage(T & 1, (T + 2) * 64);        // prefetch into just-freed buf
                asm volatile("s_waitcnt vmcnt(8)" ::: "memory");  // T+1 landed
            } else {
                asm volatile("s_waitcnt vmcnt(0)" ::: "memory");  // drain T+1
            }
            __builtin_amdgcn_s_barrier();          // T+1 data visible to all
            __builtin_amdgcn_sched_barrier(0);
        }
    }

#pragma unroll
    for (int r = 0; r < 4; ++r)
        for (int off = 1; off < 16; off <<= 1) lsum[r] += __shfl_xor(lsum[r], off);

    float inv[4];
#pragma unroll
    for (int r = 0; r < 4; ++r) inv[r] = 1.f / lsum[r];

    u16* optr = O + (size_t)(b * SEQ + q0 + w * 16) * (NH * HDIM) + h * HDIM;
#pragma unroll
    for (int c = 0; c < 8; ++c)
#pragma unroll
        for (int r = 0; r < 4; ++r)
            optr[(size_t)(q84 + r) * (NH * HDIM) + c * 16 + row16] = f2bf(o[c][r] * inv[r]);
}

extern "C" void kernel_launch(void* const* d_in, const int* in_sizes, int n_in,
                              void* d_out, int out_size, void* d_ws, size_t ws_size,
                              hipStream_t stream) {
    const float* x    = (const float*)d_in[0];   // (B*S, 4096) f32
    const float* fcos = (const float*)d_in[1];   // (S, 64) f32
    const float* fsin = (const float*)d_in[2];   // (S, 64) f32
    // d_in[3] = mask (unused: causal), d_in[8] = start_pos (0, unused)
    const float* wq = (const float*)d_in[4];     // (4096, 4096) f32
    const float* wk = (const float*)d_in[5];     // (4096, 1024) f32
    const float* wv = (const float*)d_in[6];     // (4096, 1024) f32
    const float* wo = (const float*)d_in[7];     // (4096, 4096) f32
    float* out = (float*)d_out;                  // (B*S, 4096) f32

    char* wsp = (char*)d_ws;
    // 160 MiB total via aliasing:
    u16* BTall = (u16*)(wsp);                     // 50331648 B: [wqT;wkT;wvT] (6144,4096)
    u16* VtG   = (u16*)(wsp);                     // 8388608 B, reuses BTall after QKV gemm
    u16* woT   = (u16*)(wsp + 50331648);          // 33554432 B
    u16* xb    = (u16*)(wsp + 83886080);          // 33554432 B
    u16* ATb   = (u16*)(wsp + 83886080);          // reuses xb after QKV gemm
    u16* QKVb  = (u16*)(wsp + 117440512);         // 50331648 B  (end: 167772160)

    const int M = 2 * SEQ;        // 4096 tokens
    const int D = 4096;
    const int NQ = NH * HDIM;     // 4096

    dim3 tb(32, 32);
    transcvt_k<<<dim3(4096 / 32, D / 32), tb, 0, stream>>>(wq, BTall, D, 4096);
    transcvt_k<<<dim3(1024 / 32, D / 32), tb, 0, stream>>>(wk, BTall + (size_t)4096 * 4096, D, 1024);
    transcvt_k<<<dim3(1024 / 32, D / 32), tb, 0, stream>>>(wv, BTall + (size_t)5120 * 4096, D, 1024);
    transcvt_k<<<dim3(D / 32, NQ / 32), tb, 0, stream>>>(wo, woT, NQ, D);
    cvt_k<<<(M * D) / (256 * 8), 256, 0, stream>>>(x, xb);

    // fused QKV projection: (4096,4096) @ (4096,6144) -> QKVb
    gemm256<false><<<dim3(QKVW / 256, M / 256), 512, 0, stream>>>(xb, BTall, QKVb, M, QKVW, D);

    rope_k<<<(M * NH * 64) / 256, 256, 0, stream>>>(QKVb, 0, fcos, fsin, NH);
    rope_k<<<(M * NKV * 64) / 256, 256, 0, stream>>>(QKVb, KCOL, fcos, fsin, NKV);

    vtrans_k<<<dim3(SEQ / 32, HDIM / 32, 2 * NKV), tb, 0, stream>>>(QKVb, VtG);

    fattn_k<<<dim3(SEQ / 64, NH, 2), 256, 0, stream>>>(QKVb, VtG, ATb);

    gemm256<true><<<dim3(D / 256, M / 256), 512, 0, stream>>>(ATb, woT, out, M, D, NQ);

    (void)in_sizes; (void)n_in; (void)out_size; (void)ws_size;
}

// Round 6
// 879.070 us; speedup vs baseline: 1.0155x; 1.0155x over previous
//
#include <hip/hip_runtime.h>

typedef unsigned short u16;
typedef unsigned int u32;

typedef __bf16 bf16x8 __attribute__((ext_vector_type(8)));
typedef float f32x4 __attribute__((ext_vector_type(4)));

#define SEQ 2048
#define NH 32
#define NKV 8
#define HDIM 128
#define QKVW 6144   // fused QKV row width: 4096 Q + 1024 K + 1024 V
#define KCOL 4096
#define VCOL 5120

__device__ __forceinline__ float b2f(u16 u) {
    return __uint_as_float(((u32)u) << 16);
}
__device__ __forceinline__ u16 f2bf(float f) {
    u32 u = __float_as_uint(f);
    u += 0x7fff + ((u >> 16) & 1);   // RNE
    return (u16)(u >> 16);
}

#define GLDS16(g, l)                                                            \
    __builtin_amdgcn_global_load_lds(                                           \
        (const __attribute__((address_space(1))) void*)(g),                     \
        (__attribute__((address_space(3))) void*)(l), 16, 0, 0)

// ------- transpose + fp32->bf16 convert: in (K,N) f32 -> out (N,K) bf16 -----
__global__ __launch_bounds__(1024) void transcvt_k(const float* __restrict__ in,
                                                   u16* __restrict__ out,
                                                   int K, int N) {
    __shared__ float tile[32][33];
    int n0 = blockIdx.x * 32, k0 = blockIdx.y * 32;
    tile[threadIdx.y][threadIdx.x] = in[(size_t)(k0 + threadIdx.y) * N + n0 + threadIdx.x];
    __syncthreads();
    out[(size_t)(n0 + threadIdx.y) * K + k0 + threadIdx.x] = f2bf(tile[threadIdx.x][threadIdx.y]);
}

// ---------------- fp32 -> bf16 convert, 8 elems/thread ----------------------
__global__ __launch_bounds__(256) void cvt_k(const float* __restrict__ in,
                                             u16* __restrict__ out) {
    size_t i = ((size_t)blockIdx.x * 256 + threadIdx.x) * 8;
    float4 f0 = *(const float4*)(in + i);
    float4 f1 = *(const float4*)(in + i + 4);
    union { uint4 u4; u16 h[8]; } pk;
    pk.h[0] = f2bf(f0.x); pk.h[1] = f2bf(f0.y);
    pk.h[2] = f2bf(f0.z); pk.h[3] = f2bf(f0.w);
    pk.h[4] = f2bf(f1.x); pk.h[5] = f2bf(f1.y);
    pk.h[6] = f2bf(f1.z); pk.h[7] = f2bf(f1.w);
    *(uint4*)(out + i) = pk.u4;
}

// ---- 256x256-tile 8-phase GEMM: C(M,N) = A(M,K) @ BT(N,K)^T, bf16 in ------
// m201 template: 512 thr / 8 waves (2Mx4N), BK=64, 128 KiB double-buffered
// LDS, XOR-swizzled rows (T2), counted vmcnt (T3+T4), setprio (T5).
// Requires M%256==0, N%256==0, K%128==0.
template <bool OUT_F32>
__global__ __launch_bounds__(512, 2) void gemm256(const u16* __restrict__ A,
                                                  const u16* __restrict__ BT,
                                                  void* __restrict__ Cv,
                                                  int M, int N, int K) {
    // [buf][ A 32KB | B 32KB ] x2 = 128 KiB. Row-major [256][64] bf16,
    // 128-B rows, read-side swizzle byte ^= ((row&7)<<4) (staged via
    // pre-swizzled global source: rule #21 both-sides-or-neither).
    __shared__ __align__(16) char L[131072];
    const int t = threadIdx.x, lane = t & 63, w = t >> 6;
    const int wr = w >> 2, wc = w & 3;          // wave grid 2(M) x 4(N)
    const int m0 = blockIdx.y * 256, n0 = blockIdx.x * 256;
    const int r16 = lane & 15;
    const int woff = w * 1024;                  // per-wave slot in each 8KB issue
    const int w8l = w * 8 + (lane >> 3);        // row within a 64-row issue block
    const int cswz = ((lane & 7) ^ (lane >> 3)) * 8;  // pre-swizzled src col (elems)
    const u16* sA = A + (size_t)(m0 + w8l) * K + cswz;
    const u16* sB = BT + (size_t)(n0 + w8l) * K + cswz;

    // read-side swizzled in-row byte offsets for kk=0 / kk=1 (32-col k slices)
    const int acol0 = ((lane >> 4) * 16) ^ ((lane & 7) << 4);
    const int acol1 = (((lane >> 4) * 16) + 64) ^ ((lane & 7) << 4);
    const char* arowp = L + (wr * 128 + r16) * 128;          // A frag row base
    const char* browp = L + 32768 + (wc * 64 + r16) * 128;   // B frag row base

    f32x4 acc[8][4] = {};
    bf16x8 a[4][2], b0[2][2], b1[2][2];

    // stage one half-tile (128 rows = 2 x 8KB issues) of A (isB=0) or B (isB=1)
    auto stage = [&](int bufi, int isB, int h, int kt) {
        const u16* s = isB ? sB : sA;
        char* d = (char*)L + bufi * 65536 + isB * 32768 + h * 16384 + woff;
        GLDS16(s + (size_t)(h * 128) * K + kt, d);
        GLDS16(s + (size_t)(h * 128 + 64) * K + kt, d + 8192);
    };

    const int NT = K >> 6;
    // prologue: tile0 fully + tile1.A0; drain tile0 (leave tile1.A0 in flight)
    stage(0, 0, 0, 0); stage(0, 0, 1, 0); stage(0, 1, 0, 0); stage(0, 1, 1, 0);
    if (NT > 1) {
        stage(1, 0, 0, 64);
        asm volatile("s_waitcnt vmcnt(2)" ::: "memory");
    } else {
        asm volatile("s_waitcnt vmcnt(0)" ::: "memory");
    }
    __builtin_amdgcn_s_barrier();
    __builtin_amdgcn_sched_barrier(0);

    for (int T = 0; T < NT; ++T) {
        const int buf = T & 1;
        const char* Ab = arowp + buf * 65536;
        const char* Bb = browp + buf * 65536;
        const int ktn = (T + 1) << 6, ktn2 = (T + 2) << 6;

        // ---------------- P1: a[0-3], b[0-1]  |  stage (T+1).A1 ----------------
#pragma unroll
        for (int mi = 0; mi < 4; ++mi) {
            a[mi][0] = *(const bf16x8*)(Ab + mi * 2048 + acol0);
            a[mi][1] = *(const bf16x8*)(Ab + mi * 2048 + acol1);
        }
#pragma unroll
        for (int ni = 0; ni < 2; ++ni) {
            b0[ni][0] = *(const bf16x8*)(Bb + ni * 2048 + acol0);
            b0[ni][1] = *(const bf16x8*)(Bb + ni * 2048 + acol1);
        }
        if (T + 1 < NT) stage(buf ^ 1, 0, 1, ktn);
        __builtin_amdgcn_s_barrier();
        __builtin_amdgcn_sched_barrier(0);
        asm volatile("s_waitcnt lgkmcnt(0)" ::: "memory");
        __builtin_amdgcn_s_setprio(1);
#pragma unroll
        for (int mi = 0; mi < 4; ++mi)
#pragma unroll
            for (int ni = 0; ni < 2; ++ni) {
                acc[mi][ni] = __builtin_amdgcn_mfma_f32_16x16x32_bf16(a[mi][0], b0[ni][0], acc[mi][ni], 0, 0, 0);
                acc[mi][ni] = __builtin_amdgcn_mfma_f32_16x16x32_bf16(a[mi][1], b0[ni][1], acc[mi][ni], 0, 0, 0);
            }
        __builtin_amdgcn_s_setprio(0);
        __builtin_amdgcn_s_barrier();
        __builtin_amdgcn_sched_barrier(0);

        // ---------------- P2: b[2-3]          |  stage (T+1).B0 ----------------
#pragma unroll
        for (int ni = 0; ni < 2; ++ni) {
            b1[ni][0] = *(const bf16x8*)(Bb + (ni + 2) * 2048 + acol0);
            b1[ni][1] = *(const bf16x8*)(Bb + (ni + 2) * 2048 + acol1);
        }
        if (T + 1 < NT) stage(buf ^ 1, 1, 0, ktn);
        __builtin_amdgcn_s_barrier();
        __builtin_amdgcn_sched_barrier(0);
        asm volatile("s_waitcnt lgkmcnt(0)" ::: "memory");
        __builtin_amdgcn_s_setprio(1);
#pragma unroll
        for (int mi = 0; mi < 4; ++mi)
#pragma unroll
            for (int ni = 0; ni < 2; ++ni) {
                acc[mi][ni + 2] = __builtin_amdgcn_mfma_f32_16x16x32_bf16(a[mi][0], b1[ni][0], acc[mi][ni + 2], 0, 0, 0);
                acc[mi][ni + 2] = __builtin_amdgcn_mfma_f32_16x16x32_bf16(a[mi][1], b1[ni][1], acc[mi][ni + 2], 0, 0, 0);
            }
        __builtin_amdgcn_s_setprio(0);
        __builtin_amdgcn_s_barrier();
        __builtin_amdgcn_sched_barrier(0);

        // ---------------- P3: a[4-7]          |  stage (T+1).B1 ----------------
        // (last ds_reads of buf this tile)
#pragma unroll
        for (int mi = 0; mi < 4; ++mi) {
            a[mi][0] = *(const bf16x8*)(Ab + (mi + 4) * 2048 + acol0);
            a[mi][1] = *(const bf16x8*)(Ab + (mi + 4) * 2048 + acol1);
        }
        if (T + 1 < NT) stage(buf ^ 1, 1, 1, ktn);
        __builtin_amdgcn_s_barrier();
        __builtin_amdgcn_sched_barrier(0);
        asm volatile("s_waitcnt lgkmcnt(0)" ::: "memory");
        __builtin_amdgcn_s_setprio(1);
#pragma unroll
        for (int mi = 0; mi < 4; ++mi)
#pragma unroll
            for (int ni = 0; ni < 2; ++ni) {
                acc[mi + 4][ni] = __builtin_amdgcn_mfma_f32_16x16x32_bf16(a[mi][0], b0[ni][0], acc[mi + 4][ni], 0, 0, 0);
                acc[mi + 4][ni] = __builtin_amdgcn_mfma_f32_16x16x32_bf16(a[mi][1], b0[ni][1], acc[mi + 4][ni], 0, 0, 0);
            }
        __builtin_amdgcn_s_setprio(0);
        __builtin_amdgcn_s_barrier();
        __builtin_amdgcn_sched_barrier(0);

        // ---------------- P4: (no reads)      |  stage (T+2).A0 into buf -------
        // safe: all waves' reads of buf completed before P3's closing barrier.
        if (T + 2 < NT) stage(buf, 0, 0, ktn2);
        __builtin_amdgcn_s_setprio(1);
#pragma unroll
        for (int mi = 0; mi < 4; ++mi)
#pragma unroll
            for (int ni = 0; ni < 2; ++ni) {
                acc[mi + 4][ni + 2] = __builtin_amdgcn_mfma_f32_16x16x32_bf16(a[mi][0], b1[ni][0], acc[mi + 4][ni + 2], 0, 0, 0);
                acc[mi + 4][ni + 2] = __builtin_amdgcn_mfma_f32_16x16x32_bf16(a[mi][1], b1[ni][1], acc[mi + 4][ni + 2], 0, 0, 0);
            }
        __builtin_amdgcn_s_setprio(0);
        // counted drain: tile T+1 fully landed; (T+2).A0 (2 loads) stays in flight
        if (T + 2 < NT) asm volatile("s_waitcnt vmcnt(2)" ::: "memory");
        else            asm volatile("s_waitcnt vmcnt(0)" ::: "memory");
        __builtin_amdgcn_s_barrier();
        __builtin_amdgcn_sched_barrier(0);
    }

    const int r0 = (lane >> 4) * 4;
#pragma unroll
    for (int mi = 0; mi < 8; ++mi) {
#pragma unroll
        for (int r = 0; r < 4; ++r) {
            size_t row = (size_t)(m0 + wr * 128 + mi * 16 + r0 + r) * N + n0 + wc * 64;
#pragma unroll
            for (int ni = 0; ni < 4; ++ni) {
                if constexpr (OUT_F32)
                    ((float*)Cv)[row + ni * 16 + r16] = acc[mi][ni][r];
                else
                    ((u16*)Cv)[row + ni * 16 + r16] = f2bf(acc[mi][ni][r]);
            }
        }
    }
}

// ------------- RoPE in-place on QKV buffer (row stride QKVW) ----------------
__global__ __launch_bounds__(256) void rope_k(u16* __restrict__ T, int col0,
                                              const float* __restrict__ cosb,
                                              const float* __restrict__ sinb,
                                              int nh) {
    int i = blockIdx.x * 256 + threadIdx.x;
    int p = i & 63;
    int h = (i >> 6) % nh;
    int bs = i / (64 * nh);
    int s = bs & (SEQ - 1);
    size_t base = (size_t)bs * QKVW + col0 + h * HDIM + 2 * p;
    ushort2 v = *(ushort2*)(T + base);
    float te = b2f(v.x), to = b2f(v.y);
    float c = cosb[s * 64 + p], sn = sinb[s * 64 + p];
    ushort2 o;
    o.x = f2bf(te * c - to * sn);
    o.y = f2bf(te * sn + to * c);
    *(ushort2*)(T + base) = o;
}

// ---- V transpose: QKV[token][VCOL + g*128 + d] -> VtG[(b*8+g)*128 + d][s] ---
__global__ __launch_bounds__(1024) void vtrans_k(const u16* __restrict__ QKV,
                                                 u16* __restrict__ VtG) {
    __shared__ u16 tile[32][33];
    int s0 = blockIdx.x * 32, d0 = blockIdx.y * 32, plane = blockIdx.z;
    int b = plane >> 3, g = plane & 7;
    tile[threadIdx.y][threadIdx.x] =
        QKV[(size_t)(b * SEQ + s0 + threadIdx.y) * QKVW + VCOL + g * HDIM + d0 + threadIdx.x];
    __syncthreads();
    VtG[((size_t)plane * HDIM + d0 + threadIdx.y) * SEQ + s0 + threadIdx.x] =
        tile[threadIdx.x][threadIdx.y];
}

// --------- MFMA flash attention: 4 waves, 64 Q-rows, KVBLK=64 ---------------
// Tile-level software pipeline: QK^T of tile T+1 (independent MFMA) overlaps
// softmax+PV of tile T; K/V staged via global_load_lds (XOR swizzle), dbuf,
// counted vmcnt(4) so K(T+2)/V(T+1) land one full iteration before use.
__global__ __launch_bounds__(256) void fattn_k(const u16* __restrict__ QKV,
                                               const u16* __restrict__ VtG,
                                               u16* __restrict__ O) {
    // K: 2 x 16 KB @ 0 | V^T: 2 x 16 KB @ 32768 | Ps: 4 x [16][72] u16 @ 65536
    __shared__ __align__(16) char L[74752];

    const int q0 = (gridDim.x - 1 - blockIdx.x) * 64;  // big tiles first (LPT)
    const int h = blockIdx.y, b = blockIdx.z;
    const int g = h >> 2;  // N_REP = 4
    const int t = threadIdx.x, lane = t & 63, w = t >> 6;
    const int row16 = lane & 15, g16 = lane >> 4;
    const int q8 = g16 * 8, q84 = g16 * 4;
    const int swz = (row16 & 7) << 4;                 // read-side XOR (bytes)
    const float scale = 0.08838834764831845f;  // 1/sqrt(128)

    u16* Ps = (u16*)(L + 65536) + w * (16 * 72);      // 144-B rows (9x16B)

    const u16* kbase = QKV + (size_t)b * SEQ * QKVW + KCOL + g * HDIM;
    const u16* vtp = VtG + (size_t)(b * NKV + g) * HDIM * SEQ;

    // Q fragments (oldest VMEM ops; prologue vmcnt covers them)
    bf16x8 qf[4];
    {
        const u16* qptr = QKV + (size_t)(b * SEQ + q0 + w * 16 + row16) * QKVW + h * HDIM;
#pragma unroll
        for (int c = 0; c < 4; ++c) qf[c] = *(const bf16x8*)(qptr + c * 32 + q8);
    }

    // staging: 16 x 1KB issues each for K and V^T; wave w does issues w*4..w*4+3.
    // LDS slot s of row r holds global 16B-chunk s ^ (r&7)  (T2 involution).
    const int krl = lane >> 4, kch = lane & 15;       // K: 4 rows/issue, 16 chunks
    const int vrl = lane >> 3, vch = lane & 7;        // V: 8 rows/issue,  8 chunks
    auto stageK = [&](int bufi, int jb) {
#pragma unroll
        for (int jj = 0; jj < 4; ++jj) {
            int j = w * 4 + jj;
            int r = j * 4 + krl;
            int sc = kch ^ (r & 7);
            GLDS16(kbase + (size_t)(jb + r) * QKVW + sc * 8,
                   (char*)L + bufi * 16384 + j * 1024);
        }
    };
    auto stageV = [&](int bufi, int jb) {
#pragma unroll
        for (int jj = 0; jj < 4; ++jj) {
            int j = w * 4 + jj;
            int r = j * 8 + vrl;
            int sc = vch ^ (vrl & 7);
            GLDS16(vtp + (size_t)r * SEQ + jb + sc * 8,
                   (char*)L + 32768 + bufi * 16384 + j * 1024);
        }
    };
    // QK^T for one 64-wide K tile from K-buf base Kb -> sa[4]
    auto qkt = [&](const char* Kb, f32x4* sa) {
#pragma unroll
        for (int sub = 0; sub < 4; ++sub) {
            sa[sub] = (f32x4){0.f, 0.f, 0.f, 0.f};
            const int srow = sub * 16 + row16;
#pragma unroll
            for (int c = 0; c < 4; ++c) {
                bf16x8 kf = *(const bf16x8*)(Kb + srow * 256 + (((c * 4 + g16) << 4) ^ swz));
                sa[sub] = __builtin_amdgcn_mfma_f32_16x16x32_bf16(qf[c], kf, sa[sub], 0, 0, 0);
            }
        }
    };

    f32x4 o[8];
#pragma unroll
    for (int c = 0; c < 8; ++c) o[c] = (f32x4){0.f, 0.f, 0.f, 0.f};
    float lsum[4] = {0.f, 0.f, 0.f, 0.f};
    f32x4 scur[4], snext[4];

    const int NT = q0 / 64 + 1;
    // prologue: stage tiles 0 and 1; drain to V(1) (K1 landed for iter-0 QKT)
    stageK(0, 0); stageV(0, 0);
    if (NT > 1) {
        stageK(1, 64); stageV(1, 64);
        asm volatile("s_waitcnt vmcnt(4)" ::: "memory");
    } else {
        asm volatile("s_waitcnt vmcnt(0)" ::: "memory");
    }
    __builtin_amdgcn_s_barrier();
    __builtin_amdgcn_sched_barrier(0);
    qkt((const char*)L, scur);                 // tile 0 scores
    __builtin_amdgcn_s_barrier();              // K-buf0 free for iter-0 restage
    __builtin_amdgcn_sched_barrier(0);

    for (int T = 0; T < NT; ++T) {
        const int jb = T * 64;
        // restage K(T+2) into K-buf[T&1] (last read at top of iter T-1)
        if (T + 2 < NT) stageK(T & 1, jb + 128);
        // QK^T for tile T+1 — independent of tile T's softmax/PV below
        __builtin_amdgcn_s_setprio(1);
        if (T + 1 < NT) qkt((const char*)L + ((T + 1) & 1) * 16384, snext);
        __builtin_amdgcn_s_setprio(0);

        // softmax on scur (tile T), P -> per-wave LDS
#pragma unroll
        for (int sub = 0; sub < 4; ++sub) {
            const int kcol = jb + sub * 16 + row16;
            const int qrow = q0 + w * 16 + q84;
#pragma unroll
            for (int r = 0; r < 4; ++r) {
                float p = (kcol <= qrow + r) ? __expf(fminf(scur[sub][r] * scale, 80.f)) : 0.f;
                lsum[r] += p;
                Ps[(q84 + r) * 72 + sub * 16 + row16] = f2bf(p);
            }
        }
        // P·V (per-wave Ps: same-wave ordering, no barrier needed)
        const char* Vb = (const char*)L + 32768 + (T & 1) * 16384;
#pragma unroll
        for (int kk = 0; kk < 2; ++kk) {
            bf16x8 pf = *(const bf16x8*)(Ps + row16 * 72 + kk * 32 + q8);
            __builtin_amdgcn_s_setprio(1);
#pragma unroll
            for (int c = 0; c < 8; ++c) {
                bf16x8 vf = *(const bf16x8*)(Vb + (c * 16 + row16) * 128 + (((kk * 4 + g16) << 4) ^ swz));
                o[c] = __builtin_amdgcn_mfma_f32_16x16x32_bf16(pf, vf, o[c], 0, 0, 0);
            }
            __builtin_amdgcn_s_setprio(0);
        }

        if (T + 1 < NT) {
            __builtin_amdgcn_s_barrier();      // all waves done: PV(T) + QKT(T+1)
            __builtin_amdgcn_sched_barrier(0);
            if (T + 2 < NT) {
                stageV(T & 1, jb + 128);       // restage V(T+2) into freed buf
                // leave only V(T+2) in flight: K(T+2) + V(T+1) + older all landed
                asm volatile("s_waitcnt vmcnt(4)" ::: "memory");
            } else {
                asm volatile("s_waitcnt vmcnt(0)" ::: "memory");
            }
            __builtin_amdgcn_s_barrier();
            __builtin_amdgcn_sched_barrier(0);
        }
#pragma unroll
        for (int s = 0; s < 4; ++s) scur[s] = snext[s];
    }

#pragma unroll
    for (int r = 0; r < 4; ++r)
        for (int off = 1; off < 16; off <<= 1) lsum[r] += __shfl_xor(lsum[r], off);

    float inv[4];
#pragma unroll
    for (int r = 0; r < 4; ++r) inv[r] = 1.f / lsum[r];

    u16* optr = O + (size_t)(b * SEQ + q0 + w * 16) * (NH * HDIM) + h * HDIM;
#pragma unroll
    for (int c = 0; c < 8; ++c)
#pragma unroll
        for (int r = 0; r < 4; ++r)
            optr[(size_t)(q84 + r) * (NH * HDIM) + c * 16 + row16] = f2bf(o[c][r] * inv[r]);
}

extern "C" void kernel_launch(void* const* d_in, const int* in_sizes, int n_in,
                              void* d_out, int out_size, void* d_ws, size_t ws_size,
                              hipStream_t stream) {
    const float* x    = (const float*)d_in[0];   // (B*S, 4096) f32
    const float* fcos = (const float*)d_in[1];   // (S, 64) f32
    const float* fsin = (const float*)d_in[2];   // (S, 64) f32
    // d_in[3] = mask (unused: causal), d_in[8] = start_pos (0, unused)
    const float* wq = (const float*)d_in[4];     // (4096, 4096) f32
    const float* wk = (const float*)d_in[5];     // (4096, 1024) f32
    const float* wv = (const float*)d_in[6];     // (4096, 1024) f32
    const float* wo = (const float*)d_in[7];     // (4096, 4096) f32
    float* out = (float*)d_out;                  // (B*S, 4096) f32

    char* wsp = (char*)d_ws;
    // 160 MiB total via aliasing:
    u16* BTall = (u16*)(wsp);                     // 50331648 B: [wqT;wkT;wvT] (6144,4096)
    u16* VtG   = (u16*)(wsp);                     // 8388608 B, reuses BTall after QKV gemm
    u16* woT   = (u16*)(wsp + 50331648);          // 33554432 B
    u16* xb    = (u16*)(wsp + 83886080);          // 33554432 B
    u16* ATb   = (u16*)(wsp + 83886080);          // reuses xb after QKV gemm
    u16* QKVb  = (u16*)(wsp + 117440512);         // 50331648 B  (end: 167772160)

    const int M = 2 * SEQ;        // 4096 tokens
    const int D = 4096;
    const int NQ = NH * HDIM;     // 4096

    dim3 tb(32, 32);
    transcvt_k<<<dim3(4096 / 32, D / 32), tb, 0, stream>>>(wq, BTall, D, 4096);
    transcvt_k<<<dim3(1024 / 32, D / 32), tb, 0, stream>>>(wk, BTall + (size_t)4096 * 4096, D, 1024);
    transcvt_k<<<dim3(1024 / 32, D / 32), tb, 0, stream>>>(wv, BTall + (size_t)5120 * 4096, D, 1024);
    transcvt_k<<<dim3(D / 32, NQ / 32), tb, 0, stream>>>(wo, woT, NQ, D);
    cvt_k<<<(M * D) / (256 * 8), 256, 0, stream>>>(x, xb);

    // fused QKV projection: (4096,4096) @ (4096,6144) -> QKVb
    gemm256<false><<<dim3(QKVW / 256, M / 256), 512, 0, stream>>>(xb, BTall, QKVb, M, QKVW, D);

    rope_k<<<(M * NH * 64) / 256, 256, 0, stream>>>(QKVb, 0, fcos, fsin, NH);
    rope_k<<<(M * NKV * 64) / 256, 256, 0, stream>>>(QKVb, KCOL, fcos, fsin, NKV);

    vtrans_k<<<dim3(SEQ / 32, HDIM / 32, 2 * NKV), tb, 0, stream>>>(QKVb, VtG);

    fattn_k<<<dim3(SEQ / 64, NH, 2), 256, 0, stream>>>(QKVb, VtG, ATb);

    gemm256<true><<<dim3(D / 256, M / 256), 512, 0, stream>>>(ATb, woT, out, M, D, NQ);

    (void)in_sizes; (void)n_in; (void)out_size; (void)ws_size;
}